// Round 4
// baseline (479.110 us; speedup 1.0000x reference)
//
#include <hip/hip_runtime.h>
#include <math.h>

#define B_   32
#define L_   256
#define S_   64
#define D_   128
#define H_   4
#define DH_  32
#define NTOK (B_*L_)   // 8192

// ---------------------------------------------------------------------------
// ws layout (bytes):
//   [0, +16MB)  qk[NTOK][4][128]  (f32)  scaled kw_h^T q_h
//   then        cbias[NTOK][4]    (f32)  scaled q_h . kb_h
//   then        ctx[NTOK][128]    (f32)  pre-out-proj context
// ---------------------------------------------------------------------------
#define QK_OFF   0
#define QK_BYTES ((size_t)NTOK*512*4)
#define CB_OFF   (QK_OFF + QK_BYTES)
#define CB_BYTES ((size_t)NTOK*4*4)
#define CTX_OFF  (CB_OFF + CB_BYTES)

// ---------------------------------------------------------------------------
// Kernel B: per token  q = qw x + qb ;  qk_h = scale*kw_h^T q_h ;
//           cbias_h = scale * q_h . kb_h
// 32 tokens per block, 256 threads.
// ---------------------------------------------------------------------------
__global__ __launch_bounds__(256) void qk_kernel(
        const float* __restrict__ h_wq,
        const float* __restrict__ in_proj_w, const float* __restrict__ in_proj_b,
        float* __restrict__ qk_out, float* __restrict__ cb_out) {
    __shared__ float x_lds[32*128];
    __shared__ float q_lds[32*128];
    const int t0 = blockIdx.x * 32;
    const int tid = threadIdx.x;

    { // stage 32 token rows of h_wq
        const float4* src = (const float4*)(h_wq + (size_t)t0*128);
        float4* dst = (float4*)x_lds;
        for (int e = tid; e < 32*32; e += 256) dst[e] = src[e];
    }
    __syncthreads();

    const int d = tid & 127, half = tid >> 7;
    const float* xb = x_lds + half*16*128;
    { // Q projection: thread (d,half) computes q[d] for 16 tokens
        float acc[16];
        const float qb = in_proj_b[d];
        #pragma unroll
        for (int t = 0; t < 16; ++t) acc[t] = qb;
        const float4* wrow = (const float4*)(in_proj_w + (size_t)d*128);
        for (int j4 = 0; j4 < 32; ++j4) {
            float4 w = wrow[j4];
            #pragma unroll
            for (int t = 0; t < 16; ++t) {
                float4 x = *(const float4*)(xb + t*128 + j4*4);
                acc[t] += w.x*x.x + w.y*x.y + w.z*x.z + w.w*x.w;
            }
        }
        #pragma unroll
        for (int t = 0; t < 16; ++t) q_lds[(half*16+t)*128 + d] = acc[t];
    }
    __syncthreads();

    const float scale = 0.17677669529663687f;  // 1/sqrt(32)
    const float* qbse = q_lds + half*16*128;
    #pragma unroll
    for (int h = 0; h < 4; ++h) {   // qk_h[d] (coalesced kw column access)
        float acc[16];
        #pragma unroll
        for (int t = 0; t < 16; ++t) acc[t] = 0.f;
        for (int j = 0; j < 32; ++j) {
            float w = in_proj_w[(size_t)(128 + h*32 + j)*128 + d];
            #pragma unroll
            for (int t = 0; t < 16; ++t) acc[t] += w * qbse[t*128 + h*32 + j];
        }
        #pragma unroll
        for (int t = 0; t < 16; ++t)
            qk_out[(size_t)(t0 + half*16 + t)*512 + h*128 + d] = acc[t] * scale;
    }
    if (tid < 128) { // cbias
        int t = tid >> 2, h = tid & 3;
        float s = 0.f;
        for (int j = 0; j < 32; ++j)
            s += q_lds[t*128 + h*32 + j] * in_proj_b[128 + h*32 + j];
        cb_out[(t0 + t)*4 + h] = s * scale;
    }
}

// ---------------------------------------------------------------------------
// Kernel C: attention core. One block per token (b,l), 128 threads.
// No rows staging (scores stream h_all from HBM, u-accum re-reads via L2) ->
// LDS ~5.5 KB -> wave-cap occupancy (16 blocks/CU). Mask computed in-block
// by wave 0 (ballot), removing the separate mask kernel.
// qk_lds padded to stride 132 so the 4-head quad reads hit 4 distinct banks.
// ---------------------------------------------------------------------------
__global__ __launch_bounds__(128) void attn_kernel(
        const float* __restrict__ h_all,
        const float* __restrict__ in_proj_w, const float* __restrict__ in_proj_b,
        const float* __restrict__ qk_buf, const float* __restrict__ cb_buf,
        const int* __restrict__ station_id, const float* __restrict__ adj,
        float* __restrict__ ctx_out) {
    __shared__ float qk_lds[4*132];
    __shared__ float sc[4*64];
    __shared__ float u_lds[4*128];
    __shared__ int   lst[64];
    __shared__ int   cnt_s;
    __shared__ float cb[4];

    const int t = blockIdx.x;
    const int b = t >> 8;             // L_ == 256
    const int tid = threadIdx.x;

    #pragma unroll
    for (int h = 0; h < 4; ++h)
        qk_lds[h*132 + tid] = qk_buf[(size_t)t*512 + h*128 + tid];
    if (tid < 4) cb[tid] = cb_buf[t*4 + tid];

    if (tid < 64) { // wave 0: allowed-mask ballot -> compacted list
        int sid = station_id[b];
        int s = tid;
        bool av = (adj[sid*S_ + s] > 0.0f) && (s != sid);
        unsigned long long m = __ballot(av);
        if (m == 0ull) { av = (s != sid); m = __ballot(av); }   // fallback: all-but-self
        if (m == 0ull) { av = (s == sid); m = __ballot(av); }   // S==1 safety
        int idx = __popcll(m & ((1ull << s) - 1ull));
        if (av) lst[idx] = s;
        if (s == 0) cnt_s = __popcll(m);
    }
    __syncthreads();
    const int cnt = cnt_s;
    const float* rowbase = h_all + (size_t)t * (S_*D_);

    // scores: p = h + 4*i; quad shares row i (global, first HBM touch)
    for (int p = tid; p < 4*cnt; p += 128) {
        int h = p & 3, i = p >> 2;
        float acc = cb[h];
        const float4* qr = (const float4*)(qk_lds + h*132);
        const float4* rr = (const float4*)(rowbase + lst[i]*D_);
        #pragma unroll 8
        for (int j = 0; j < 32; ++j) {
            float4 a = qr[j], x = rr[j];
            acc += a.x*x.x + a.y*x.y + a.z*x.z + a.w*x.w;
        }
        sc[h*64 + i] = acc;
    }
    __syncthreads();

    { // softmax: 4 groups of 32 lanes, one head each
        int h = tid >> 5, j = tid & 31;
        float v0 = (j < cnt)      ? sc[h*64 + j]      : -INFINITY;
        float v1 = (j + 32 < cnt) ? sc[h*64 + j + 32] : -INFINITY;
        float m = fmaxf(v0, v1);
        for (int o = 16; o >= 1; o >>= 1) m = fmaxf(m, __shfl_xor(m, o, 32));
        float e0 = (j < cnt)      ? __expf(v0 - m) : 0.f;
        float e1 = (j + 32 < cnt) ? __expf(v1 - m) : 0.f;
        float ssum = e0 + e1;
        for (int o = 16; o >= 1; o >>= 1) ssum += __shfl_xor(ssum, o, 32);
        float inv = 1.0f / ssum;
        sc[h*64 + j]      = e0 * inv;
        sc[h*64 + j + 32] = e1 * inv;
    }
    __syncthreads();

    { // u_h[d] = sum_i w[h][i] * rows[i][d]  (coalesced 512B reads, L2-hot)
        float u0=0.f, u1=0.f, u2=0.f, u3=0.f;
        for (int i = 0; i < cnt; ++i) {
            float xv = rowbase[lst[i]*D_ + tid];
            u0 += sc[i]       * xv;
            u1 += sc[64 + i]  * xv;
            u2 += sc[128 + i] * xv;
            u3 += sc[192 + i] * xv;
        }
        u_lds[tid] = u0; u_lds[128+tid] = u1; u_lds[256+tid] = u2; u_lds[384+tid] = u3;
    }
    __syncthreads();

    { // ctx[d] = vb[d] + vw[d] . u_{d>>5}   (float4 streams, per-lane rows)
        int h = tid >> 5;
        const float4* vwrow = (const float4*)(in_proj_w + (size_t)(256 + tid)*128);
        const float4* ur = (const float4*)(u_lds + h*128);
        float acc = in_proj_b[256 + tid];
        #pragma unroll 8
        for (int j = 0; j < 32; ++j) {
            float4 w = vwrow[j], u = ur[j];
            acc += w.x*u.x + w.y*u.y + w.z*u.z + w.w*u.w;
        }
        ctx_out[(size_t)t*128 + tid] = acc;
    }
}

// ---------------------------------------------------------------------------
// Kernel D: out-proj + gate + residual + LayerNorm. 32 tokens/block, 256 thr.
// ---------------------------------------------------------------------------
__global__ __launch_bounds__(256) void epi_kernel(
        const float* __restrict__ h_wq, const float* __restrict__ ctx_buf,
        const float* __restrict__ out_w, const float* __restrict__ out_b,
        const float* __restrict__ gate_w, const float* __restrict__ gate_b,
        const float* __restrict__ ln_g, const float* __restrict__ ln_b,
        const float* __restrict__ alpha, float* __restrict__ out) {
    __shared__ float c_tile[32*128];  // ctx, later y
    __shared__ float x_tile[32*128];
    __shared__ float o_tile[32*128];
    __shared__ float mu_s[32], rs_s[32];
    const int t0 = blockIdx.x * 32;
    const int tid = threadIdx.x;

    {
        const float4* cs = (const float4*)(ctx_buf + (size_t)t0*128);
        const float4* xs = (const float4*)(h_wq + (size_t)t0*128);
        float4* cd = (float4*)c_tile; float4* xd = (float4*)x_tile;
        for (int e = tid; e < 32*32; e += 256) { cd[e] = cs[e]; xd[e] = xs[e]; }
    }
    __syncthreads();

    const int d = tid & 127, half = tid >> 7;
    float o_acc[16];
    { // out-proj (float4 weight stream + float4 LDS reads)
        const float ob = out_b[d];
        #pragma unroll
        for (int t = 0; t < 16; ++t) o_acc[t] = ob;
        const float4* wrow = (const float4*)(out_w + (size_t)d*128);
        const float* cbp = c_tile + half*16*128;
        for (int j4 = 0; j4 < 32; ++j4) {
            float4 w = wrow[j4];
            #pragma unroll
            for (int t = 0; t < 16; ++t) {
                float4 c = *(const float4*)(cbp + t*128 + j4*4);
                o_acc[t] += w.x*c.x + w.y*c.y + w.z*c.z + w.w*c.w;
            }
        }
        #pragma unroll
        for (int t = 0; t < 16; ++t) o_tile[(half*16+t)*128 + d] = o_acc[t];
    }
    __syncthreads();

    { // gate + residual, write y into c_tile
        float g_acc[16];
        const float gb = gate_b[d];
        #pragma unroll
        for (int t = 0; t < 16; ++t) g_acc[t] = gb;
        const float4* wrow = (const float4*)(gate_w + (size_t)d*256);
        const float* xb = x_tile + half*16*128;
        const float* obp = o_tile + half*16*128;
        for (int j4 = 0; j4 < 32; ++j4) {
            float4 w0 = wrow[j4];
            float4 w1 = wrow[32 + j4];
            #pragma unroll
            for (int t = 0; t < 16; ++t) {
                float4 x = *(const float4*)(xb  + t*128 + j4*4);
                float4 o = *(const float4*)(obp + t*128 + j4*4);
                g_acc[t] += w0.x*x.x + w0.y*x.y + w0.z*x.z + w0.w*x.w
                          + w1.x*o.x + w1.y*o.y + w1.z*o.z + w1.w*o.w;
            }
        }
        const float al = alpha[0];
        #pragma unroll
        for (int t = 0; t < 16; ++t) {
            float g = 1.0f / (1.0f + __expf(-g_acc[t]));
            float y = xb[t*128 + d] + al * g * o_acc[t];
            c_tile[(half*16+t)*128 + d] = y;
        }
    }
    __syncthreads();

    { // LayerNorm stats: 8 lanes per token
        int tt = tid >> 3, k = tid & 7;
        const float* yr = c_tile + tt*128;
        float s = 0.f;
        for (int dd = k; dd < 128; dd += 8) s += yr[dd];
        for (int o = 4; o >= 1; o >>= 1) s += __shfl_xor(s, o, 8);
        float mu = s * (1.0f/128.0f);
        float vs = 0.f;
        for (int dd = k; dd < 128; dd += 8) { float df = yr[dd] - mu; vs += df*df; }
        for (int o = 4; o >= 1; o >>= 1) vs += __shfl_xor(vs, o, 8);
        if (k == 0) { mu_s[tt] = mu; rs_s[tt] = rsqrtf(vs*(1.0f/128.0f) + 1e-5f); }
    }
    __syncthreads();

    for (int e = tid; e < 32*128; e += 256) {
        int tt = e >> 7, dd = e & 127;
        float y = c_tile[e];
        out[(size_t)t0*128 + e] = (y - mu_s[tt]) * rs_s[tt] * ln_g[dd] + ln_b[dd];
    }
}

// ---------------------------------------------------------------------------
extern "C" void kernel_launch(void* const* d_in, const int* in_sizes, int n_in,
                              void* d_out, int out_size, void* d_ws, size_t ws_size,
                              hipStream_t stream) {
    const float* h_wq       = (const float*)d_in[0];
    const float* h_all      = (const float*)d_in[1];
    const int*   station_id = (const int*)  d_in[2];
    const float* adj        = (const float*)d_in[3];
    const float* in_proj_w  = (const float*)d_in[4];
    const float* in_proj_b  = (const float*)d_in[5];
    const float* out_w      = (const float*)d_in[6];
    const float* out_b      = (const float*)d_in[7];
    const float* gate_w     = (const float*)d_in[8];
    const float* gate_b     = (const float*)d_in[9];
    const float* ln_g       = (const float*)d_in[10];
    const float* ln_b       = (const float*)d_in[11];
    const float* alpha      = (const float*)d_in[12];

    char* ws = (char*)d_ws;
    float* qk   = (float*)(ws + QK_OFF);
    float* cb   = (float*)(ws + CB_OFF);
    float* ctx  = (float*)(ws + CTX_OFF);
    float* out  = (float*)d_out;

    qk_kernel  <<<NTOK/32, 256, 0, stream>>>(h_wq, in_proj_w, in_proj_b, qk, cb);
    attn_kernel<<<NTOK, 128, 0, stream>>>(h_all, in_proj_w, in_proj_b, qk, cb,
                                          station_id, adj, ctx);
    epi_kernel <<<NTOK/32, 256, 0, stream>>>(h_wq, ctx, out_w, out_b, gate_w,
                                             gate_b, ln_g, ln_b, alpha, out);
}

// Round 6
// 448.026 us; speedup vs baseline: 1.0694x; 1.0694x over previous
//
#include <hip/hip_runtime.h>
#include <math.h>

#define B_   32
#define L_   256
#define S_   64
#define D_   128
#define H_   4
#define DH_  32
#define NTOK (B_*L_)   // 8192

// ws layout: qk[NTOK][4][128] f32 | cbias[NTOK][4] f32 | ctx[NTOK][128] f32
#define QK_OFF   0
#define QK_BYTES ((size_t)NTOK*512*4)
#define CB_OFF   (QK_OFF + QK_BYTES)
#define CB_BYTES ((size_t)NTOK*4*4)
#define CTX_OFF  (CB_OFF + CB_BYTES)

// ---------------------------------------------------------------------------
// Kernel B: per token  q = qw x + qb ;  qk_h = scale*kw_h^T q_h ;
//           cbias_h = scale * q_h . kb_h      (32 tokens/block, 256 thr)
// ---------------------------------------------------------------------------
__global__ __launch_bounds__(256) void qk_kernel(
        const float* __restrict__ h_wq,
        const float* __restrict__ in_proj_w, const float* __restrict__ in_proj_b,
        float* __restrict__ qk_out, float* __restrict__ cb_out) {
    __shared__ float x_lds[32*128];
    __shared__ float q_lds[32*128];
    const int t0 = blockIdx.x * 32;
    const int tid = threadIdx.x;

    { // stage 32 token rows of h_wq
        const float4* src = (const float4*)(h_wq + (size_t)t0*128);
        float4* dst = (float4*)x_lds;
        for (int e = tid; e < 32*32; e += 256) dst[e] = src[e];
    }
    __syncthreads();

    const int d = tid & 127, half = tid >> 7;
    const float* xb = x_lds + half*16*128;
    { // Q projection
        float acc[16];
        const float qb = in_proj_b[d];
        #pragma unroll
        for (int t = 0; t < 16; ++t) acc[t] = qb;
        const float4* wrow = (const float4*)(in_proj_w + (size_t)d*128);
        for (int j4 = 0; j4 < 32; ++j4) {
            float4 w = wrow[j4];
            #pragma unroll
            for (int t = 0; t < 16; ++t) {
                float4 x = *(const float4*)(xb + t*128 + j4*4);
                acc[t] += w.x*x.x + w.y*x.y + w.z*x.z + w.w*x.w;
            }
        }
        #pragma unroll
        for (int t = 0; t < 16; ++t) q_lds[(half*16+t)*128 + d] = acc[t];
    }
    __syncthreads();

    const float scale = 0.17677669529663687f;  // 1/sqrt(32)
    const float* qbse = q_lds + half*16*128;
    #pragma unroll
    for (int h = 0; h < 4; ++h) {   // qk_h[d], coalesced kw column access
        float acc[16];
        #pragma unroll
        for (int t = 0; t < 16; ++t) acc[t] = 0.f;
        for (int j = 0; j < 32; ++j) {
            float w = in_proj_w[(size_t)(128 + h*32 + j)*128 + d];
            #pragma unroll
            for (int t = 0; t < 16; ++t) acc[t] += w * qbse[t*128 + h*32 + j];
        }
        #pragma unroll
        for (int t = 0; t < 16; ++t)
            qk_out[(size_t)(t0 + half*16 + t)*512 + h*128 + d] = acc[t] * scale;
    }
    if (tid < 128) { // cbias
        int t = tid >> 2, h = tid & 3;
        float s = 0.f;
        for (int j = 0; j < 32; ++j)
            s += q_lds[t*128 + h*32 + j] * in_proj_b[128 + h*32 + j];
        cb_out[(t0 + t)*4 + h] = s * scale;
    }
}

// ---------------------------------------------------------------------------
// Kernel C: attention core, 4 tokens/block (one 64-lane wave per token for
// scores/softmax/u; wave-private phases need no barriers), then a cooperative
// ctx phase where each vw row is read ONCE per block and dotted against all 4
// tokens' u (4x less vw L2 traffic than 1 tok/block). qk/u stride 132 -> the
// 4-head quad reads land on 4 distinct banks. 2048 blocks x 256 threads.
// ---------------------------------------------------------------------------
__global__ __launch_bounds__(256) void attn_kernel(
        const float* __restrict__ h_all,
        const float* __restrict__ in_proj_w, const float* __restrict__ in_proj_b,
        const float* __restrict__ qk_buf, const float* __restrict__ cb_buf,
        const int* __restrict__ station_id, const float* __restrict__ adj,
        float* __restrict__ ctx_out) {
    __shared__ float qk_lds[4][4*132];   // [tok][h*132 + d]
    __shared__ float sc[4][4*64];        // [tok][h*64 + i]
    __shared__ float u_lds[4][4*132];    // [tok][h*132 + d]
    __shared__ int   lst[64];
    __shared__ int   cnt_s;
    __shared__ float cb[4][4];

    const int t0  = blockIdx.x * 4;      // 4 tokens, same b (4 | 256)
    const int b   = t0 >> 8;
    const int tid = threadIdx.x;
    const int wv  = tid >> 6;            // token slot 0..3
    const int lane = tid & 63;
    const int t = t0 + wv;

    if (tid < 64) { // wave 0: allowed-mask ballot -> compacted list
        int sid = station_id[b];
        int s = tid;
        bool av = (adj[sid*S_ + s] > 0.0f) && (s != sid);
        unsigned long long m = __ballot(av);
        if (m == 0ull) { av = (s != sid); m = __ballot(av); }   // all-but-self
        if (m == 0ull) { av = (s == sid); m = __ballot(av); }   // S==1 safety
        int idx = __popcll(m & ((1ull << s) - 1ull));
        if (av) lst[idx] = s;
        if (s == 0) cnt_s = __popcll(m);
    }

    { // each wave loads its token's qk row (2KB) as float4: 2 iters, 1KB/instr
        const float4* src = (const float4*)(qk_buf + (size_t)t*512);
        for (int e = lane; e < 128; e += 64) {
            int h = e >> 5, d4 = e & 31;
            *(float4*)&qk_lds[wv][h*132 + d4*4] = src[e];
        }
    }
    if (lane < 4) cb[wv][lane] = cb_buf[t*4 + lane];
    __syncthreads();               // publishes lst/cnt (and everything else)

    const int cnt = cnt_s;
    const float* rowbase = h_all + (size_t)t * (S_*D_);

    // scores (wave-private): p = h + 4*i, quad shares row i (broadcast loads)
    for (int p = lane; p < 4*cnt; p += 64) {
        int h = p & 3, i = p >> 2;
        float acc = cb[wv][h];
        const float4* qr = (const float4*)(&qk_lds[wv][h*132]);
        const float4* rr = (const float4*)(rowbase + lst[i]*D_);
        #pragma unroll 8
        for (int j = 0; j < 32; ++j) {
            float4 a = qr[j], x = rr[j];
            acc += a.x*x.x + a.y*x.y + a.z*x.z + a.w*x.w;
        }
        sc[wv][h*64 + i] = acc;
    }

    { // softmax (wave-private): two 32-lane groups, 2 heads each
        int j = lane & 31;
        for (int h = (lane >> 5); h < 4; h += 2) {
            float v0 = (j < cnt)      ? sc[wv][h*64 + j]      : -INFINITY;
            float v1 = (j + 32 < cnt) ? sc[wv][h*64 + j + 32] : -INFINITY;
            float m = fmaxf(v0, v1);
            for (int o = 16; o >= 1; o >>= 1) m = fmaxf(m, __shfl_xor(m, o, 32));
            float e0 = (j < cnt)      ? __expf(v0 - m) : 0.f;
            float e1 = (j + 32 < cnt) ? __expf(v1 - m) : 0.f;
            float ssum = e0 + e1;
            for (int o = 16; o >= 1; o >>= 1) ssum += __shfl_xor(ssum, o, 32);
            float inv = 1.0f / ssum;
            sc[wv][h*64 + j]      = e0 * inv;
            sc[wv][h*64 + j + 32] = e1 * inv;
        }
    }

    { // u-accum (wave-private): lane owns d = 2*lane, 2*lane+1 (float2 loads)
        float2 u0 = {0.f,0.f}, u1 = {0.f,0.f}, u2 = {0.f,0.f}, u3 = {0.f,0.f};
        #pragma unroll 4
        for (int i = 0; i < cnt; ++i) {
            float2 x = *(const float2*)(rowbase + lst[i]*D_ + 2*lane);
            float w0 = sc[wv][i], w1 = sc[wv][64+i], w2 = sc[wv][128+i], w3 = sc[wv][192+i];
            u0.x += w0*x.x; u0.y += w0*x.y;
            u1.x += w1*x.x; u1.y += w1*x.y;
            u2.x += w2*x.x; u2.y += w2*x.y;
            u3.x += w3*x.x; u3.y += w3*x.y;
        }
        *(float2*)&u_lds[wv][0*132 + 2*lane] = u0;
        *(float2*)&u_lds[wv][1*132 + 2*lane] = u1;
        *(float2*)&u_lds[wv][2*132 + 2*lane] = u2;
        *(float2*)&u_lds[wv][3*132 + 2*lane] = u3;
    }
    __syncthreads();

    if (tid < 128) { // ctx for all 4 tokens; vw row read ONCE per block
        const int d = tid, h = d >> 5;
        const float4* vwrow = (const float4*)(in_proj_w + (size_t)(256 + d)*128);
        const float vb = in_proj_b[256 + d];
        float a0 = vb, a1 = vb, a2 = vb, a3 = vb;
        #pragma unroll 8
        for (int j4 = 0; j4 < 32; ++j4) {
            float4 w = vwrow[j4];
            float4 u0 = *(const float4*)(&u_lds[0][h*132 + j4*4]);
            float4 u1 = *(const float4*)(&u_lds[1][h*132 + j4*4]);
            float4 u2 = *(const float4*)(&u_lds[2][h*132 + j4*4]);
            float4 u3 = *(const float4*)(&u_lds[3][h*132 + j4*4]);
            a0 += w.x*u0.x + w.y*u0.y + w.z*u0.z + w.w*u0.w;
            a1 += w.x*u1.x + w.y*u1.y + w.z*u1.z + w.w*u1.w;
            a2 += w.x*u2.x + w.y*u2.y + w.z*u2.z + w.w*u2.w;
            a3 += w.x*u3.x + w.y*u3.y + w.z*u3.z + w.w*u3.w;
        }
        ctx_out[(size_t)(t0+0)*128 + d] = a0;
        ctx_out[(size_t)(t0+1)*128 + d] = a1;
        ctx_out[(size_t)(t0+2)*128 + d] = a2;
        ctx_out[(size_t)(t0+3)*128 + d] = a3;
    }
}

// ---------------------------------------------------------------------------
// Kernel D: out-proj + gate + residual + LayerNorm. 32 tokens/block, 256 thr.
// ---------------------------------------------------------------------------
__global__ __launch_bounds__(256) void epi_kernel(
        const float* __restrict__ h_wq, const float* __restrict__ ctx_buf,
        const float* __restrict__ out_w, const float* __restrict__ out_b,
        const float* __restrict__ gate_w, const float* __restrict__ gate_b,
        const float* __restrict__ ln_g, const float* __restrict__ ln_b,
        const float* __restrict__ alpha, float* __restrict__ out) {
    __shared__ float c_tile[32*128];  // ctx, later y
    __shared__ float x_tile[32*128];
    __shared__ float o_tile[32*128];
    __shared__ float mu_s[32], rs_s[32];
    const int t0 = blockIdx.x * 32;
    const int tid = threadIdx.x;

    {
        const float4* cs = (const float4*)(ctx_buf + (size_t)t0*128);
        const float4* xs = (const float4*)(h_wq + (size_t)t0*128);
        float4* cd = (float4*)c_tile; float4* xd = (float4*)x_tile;
        for (int e = tid; e < 32*32; e += 256) { cd[e] = cs[e]; xd[e] = xs[e]; }
    }
    __syncthreads();

    const int d = tid & 127, half = tid >> 7;
    float o_acc[16];
    { // out-proj
        const float ob = out_b[d];
        #pragma unroll
        for (int t = 0; t < 16; ++t) o_acc[t] = ob;
        const float4* wrow = (const float4*)(out_w + (size_t)d*128);
        const float* cbp = c_tile + half*16*128;
        for (int j4 = 0; j4 < 32; ++j4) {
            float4 w = wrow[j4];
            #pragma unroll
            for (int t = 0; t < 16; ++t) {
                float4 c = *(const float4*)(cbp + t*128 + j4*4);
                o_acc[t] += w.x*c.x + w.y*c.y + w.z*c.z + w.w*c.w;
            }
        }
        #pragma unroll
        for (int t = 0; t < 16; ++t) o_tile[(half*16+t)*128 + d] = o_acc[t];
    }
    __syncthreads();

    { // gate + residual, write y into c_tile
        float g_acc[16];
        const float gb = gate_b[d];
        #pragma unroll
        for (int t = 0; t < 16; ++t) g_acc[t] = gb;
        const float4* wrow = (const float4*)(gate_w + (size_t)d*256);
        const float* xb = x_tile + half*16*128;
        const float* obp = o_tile + half*16*128;
        for (int j4 = 0; j4 < 32; ++j4) {
            float4 w0 = wrow[j4];
            float4 w1 = wrow[32 + j4];
            #pragma unroll
            for (int t = 0; t < 16; ++t) {
                float4 x = *(const float4*)(xb  + t*128 + j4*4);
                float4 o = *(const float4*)(obp + t*128 + j4*4);
                g_acc[t] += w0.x*x.x + w0.y*x.y + w0.z*x.z + w0.w*x.w
                          + w1.x*o.x + w1.y*o.y + w1.z*o.z + w1.w*o.w;
            }
        }
        const float al = alpha[0];
        #pragma unroll
        for (int t = 0; t < 16; ++t) {
            float g = 1.0f / (1.0f + __expf(-g_acc[t]));
            float y = xb[t*128 + d] + al * g * o_acc[t];
            c_tile[(half*16+t)*128 + d] = y;
        }
    }
    __syncthreads();

    { // LayerNorm stats: 8 lanes per token
        int tt = tid >> 3, k = tid & 7;
        const float* yr = c_tile + tt*128;
        float s = 0.f;
        for (int dd = k; dd < 128; dd += 8) s += yr[dd];
        for (int o = 4; o >= 1; o >>= 1) s += __shfl_xor(s, o, 8);
        float mu = s * (1.0f/128.0f);
        float vs = 0.f;
        for (int dd = k; dd < 128; dd += 8) { float df = yr[dd] - mu; vs += df*df; }
        for (int o = 4; o >= 1; o >>= 1) vs += __shfl_xor(vs, o, 8);
        if (k == 0) { mu_s[tt] = mu; rs_s[tt] = rsqrtf(vs*(1.0f/128.0f) + 1e-5f); }
    }
    __syncthreads();

    for (int e = tid; e < 32*128; e += 256) {
        int tt = e >> 7, dd = e & 127;
        float y = c_tile[e];
        out[(size_t)t0*128 + e] = (y - mu_s[tt]) * rs_s[tt] * ln_g[dd] + ln_b[dd];
    }
}

// ---------------------------------------------------------------------------
extern "C" void kernel_launch(void* const* d_in, const int* in_sizes, int n_in,
                              void* d_out, int out_size, void* d_ws, size_t ws_size,
                              hipStream_t stream) {
    const float* h_wq       = (const float*)d_in[0];
    const float* h_all      = (const float*)d_in[1];
    const int*   station_id = (const int*)  d_in[2];
    const float* adj        = (const float*)d_in[3];
    const float* in_proj_w  = (const float*)d_in[4];
    const float* in_proj_b  = (const float*)d_in[5];
    const float* out_w      = (const float*)d_in[6];
    const float* out_b      = (const float*)d_in[7];
    const float* gate_w     = (const float*)d_in[8];
    const float* gate_b     = (const float*)d_in[9];
    const float* ln_g       = (const float*)d_in[10];
    const float* ln_b       = (const float*)d_in[11];
    const float* alpha      = (const float*)d_in[12];

    char* ws = (char*)d_ws;
    float* qk   = (float*)(ws + QK_OFF);
    float* cb   = (float*)(ws + CB_OFF);
    float* ctx  = (float*)(ws + CTX_OFF);
    float* out  = (float*)d_out;

    qk_kernel  <<<NTOK/32, 256, 0, stream>>>(h_wq, in_proj_w, in_proj_b, qk, cb);
    attn_kernel<<<NTOK/4, 256, 0, stream>>>(h_all, in_proj_w, in_proj_b, qk, cb,
                                            station_id, adj, ctx);
    epi_kernel <<<NTOK/32, 256, 0, stream>>>(h_wq, ctx, out_w, out_b, gate_w,
                                             gate_b, ln_g, ln_b, alpha, out);
}